// Round 5
// baseline (210.345 us; speedup 1.0000x reference)
//
#include <hip/hip_runtime.h>

typedef float v2f __attribute__((ext_vector_type(2)));

// Problem constants (fixed by the reference).
#define Bc   8
#define Cc   16
#define HWc  65536              // 256*256
#define HIDc 32
#define Npix (Bc * HWc)         // 524288 pixels
#define FUSED_ELEMS (Bc * Cc * HWc)   // 8388608
#define PREF_ELEMS  (Cc * 2)          // 32
#define TPB  128
#define PPT  2                        // pixels per thread (stride TPB apart)
#define PPB  (TPB * PPT)              // 256 pixels per block
#define WSTRIDE 81                    // float2 slots per class in packed ws
#define PACKED_BYTES (Cc * WSTRIDE * 8)  // 10368 B

// ---------------------------------------------------------------------------
// Prep: hidden-pair-contiguous float2 weight layout (see R4). Per class:
//   [0..15] w1s | [16..31] w1g | [32..47] b1 | [48..63] w2_0 | [64..79] w2_1
//   [80] b2
// ---------------------------------------------------------------------------
__global__ void gate_prep(const float* __restrict__ W1, const float* __restrict__ b1,
                          const float* __restrict__ W2, const float* __restrict__ b2,
                          v2f* __restrict__ ws)
{
    const int c = blockIdx.x;
    const int j = threadIdx.x;
    v2f* wp = ws + c * WSTRIDE;
    if (j < 16) {
        wp[j]      = (v2f){W1[c*64 + 4*j + 0], W1[c*64 + 4*j + 2]};
        wp[16 + j] = (v2f){W1[c*64 + 4*j + 1], W1[c*64 + 4*j + 3]};
        wp[32 + j] = (v2f){b1[c*32 + 2*j],     b1[c*32 + 2*j + 1]};
        wp[48 + j] = (v2f){W2[c*64 + 2*j],     W2[c*64 + 2*j + 1]};
        wp[64 + j] = (v2f){W2[c*64 + 32 + 2*j],W2[c*64 + 32 + 2*j + 1]};
    } else if (j == 16) {
        wp[80] = (v2f){b2[2*c], b2[2*c + 1]};
    }
}

// ---------------------------------------------------------------------------
// Main: 2 pixels/thread (n, n+128). Halves wave count -> per-pixel weight
// s_load stream and per-pixel wave overhead halve; 2 independent chains give
// ILP for exp/SMEM/VMEM latency. Per-wave LDS + global access patterns are
// identical shapes to R4's measured-conflict-free ones.
// ---------------------------------------------------------------------------
__global__ __launch_bounds__(TPB)
__attribute__((amdgpu_waves_per_eu(2, 4)))
void gate_main_packed2(
    const float* __restrict__ swin, const float* __restrict__ gru,
    const v2f* __restrict__ wsw, const float* __restrict__ pref,
    float* __restrict__ out)
{
    __shared__ float2 dwbuf2[PPB * Cc];   // 32 KB, XOR-rotation swizzled

    const int tid  = threadIdx.x;
    const int n0   = blockIdx.x * PPB + tid;   // q=0 pixel; q=1 is n0+TPB
    const int bidx = n0 >> 16;                 // block's 256 px lie in one image
    const int hw0  = n0 & (HWc - 1);

    const float* sptr = swin + (size_t)bidx * (Cc * HWc) + hw0;
    const float* gptr = gru  + (size_t)bidx * (Cc * HWc) + hw0;

    float sl[PPT][Cc], gl[PPT][Cc];
#pragma unroll
    for (int c = 0; c < Cc; ++c) {
#pragma unroll
        for (int q = 0; q < PPT; ++q) {
            sl[q][c] = sptr[c * HWc + q * TPB];
            gl[q][c] = gptr[c * HWc + q * TPB];
        }
    }

    float es[PPT][Cc], eg[PPT][Cc];
    float invs[PPT], invg[PPT];
#pragma unroll
    for (int q = 0; q < PPT; ++q) {
        float ms = sl[q][0], mg = gl[q][0];
#pragma unroll
        for (int c = 1; c < Cc; ++c) {
            ms = fmaxf(ms, sl[q][c]);
            mg = fmaxf(mg, gl[q][c]);
        }
        float ss = 0.f, sg = 0.f;
#pragma unroll
        for (int c = 0; c < Cc; ++c) {
            es[q][c] = __expf(sl[q][c] - ms);  ss += es[q][c];
            eg[q][c] = __expf(gl[q][c] - mg);  sg += eg[q][c];
        }
        invs[q] = __builtin_amdgcn_rcpf(ss);
        invg[q] = __builtin_amdgcn_rcpf(sg);
    }

    float* fop = out + (size_t)bidx * (Cc * HWc) + hw0;

#pragma unroll
    for (int c = 0; c < Cc; ++c) {
        const v2f* wp = wsw + c * WSTRIDE;

        v2f spv[PPT], gpv[PPT], acc0[PPT], acc1[PPT];
#pragma unroll
        for (int q = 0; q < PPT; ++q) {
            const float sp = es[q][c] * invs[q];
            const float gp = eg[q][c] * invg[q];
            spv[q] = (v2f){sp, sp};
            gpv[q] = (v2f){gp, gp};
            acc0[q] = (v2f){0.f, 0.f};
            acc1[q] = (v2f){0.f, 0.f};
        }

#pragma unroll
        for (int j = 0; j < HIDc / 2; ++j) {
            // Shared weight operands for both pixels (amortizes s->v moves).
            const v2f w1s = wp[j];
            const v2f w1g = wp[16 + j];
            const v2f bb  = wp[32 + j];
            const v2f u0  = wp[48 + j];
            const v2f u1  = wp[64 + j];
#pragma unroll
            for (int q = 0; q < PPT; ++q) {
                v2f h = w1s * spv[q] + (w1g * gpv[q] + bb);
                h = __builtin_elementwise_max(h, (v2f){0.f, 0.f});
                acc0[q] = h * u0 + acc0[q];
                acc1[q] = h * u1 + acc1[q];
            }
        }
        const v2f b2v = wp[80];
#pragma unroll
        for (int q = 0; q < PPT; ++q) {
            const float a0 = acc0[q].x + acc0[q].y + b2v.x;
            const float a1 = acc1[q].x + acc1[q].y + b2v.y;

            // softmax over 2 == stable sigmoid of the difference
            const float d = a0 - a1;
            const float t = __expf(-fabsf(d));
            const float r = __builtin_amdgcn_rcpf(1.f + t);
            const float w0 = (d >= 0.f) ? r : 1.f - r;
            const float w1 = 1.f - w0;

            fop[c * HWc + q * TPB] = fmaf(w0, sl[q][c], w1 * gl[q][c]);

            const int p = tid + q * TPB;     // block-local pixel
            dwbuf2[p * Cc + ((c + p) & (Cc - 1))] = make_float2(w0, w1);
        }
    }

    __syncthreads();

    // Drain dw coalesced: block owns 4096 float2 = 32 KB of out.
    float2* outv2 = reinterpret_cast<float2*>(
        out + (size_t)FUSED_ELEMS + PREF_ELEMS + (size_t)blockIdx.x * (PPB * Cc * 2));
#pragma unroll
    for (int j = 0; j < PPB * Cc / TPB; ++j) {
        const int pi = j * TPB + tid;        // pair index in block's dw region
        const int p  = pi >> 4;              // pixel
        const int pr = pi & (Cc - 1);        // pair-in-pixel
        outv2[pi] = dwbuf2[p * Cc + ((pr + p) & (Cc - 1))];
    }

    if (blockIdx.x == 0 && tid < PREF_ELEMS) {
        out[(size_t)FUSED_ELEMS + tid] = pref[tid];
    }
}

// ---------------------------------------------------------------------------
// Fallback (R3-style scalar kernel) if ws_size is too small.
// ---------------------------------------------------------------------------
__global__ __launch_bounds__(256, 4) void gate_main_scalar(
    const float* __restrict__ swin, const float* __restrict__ gru,
    const float* __restrict__ W1, const float* __restrict__ b1,
    const float* __restrict__ W2, const float* __restrict__ b2,
    const float* __restrict__ pref, float* __restrict__ out)
{
    __shared__ float2 dwbuf2[256 * Cc];

    const int tid  = threadIdx.x;
    const int n    = blockIdx.x * 256 + tid;
    const int bidx = n >> 16;
    const int hw   = n & (HWc - 1);

    const float* sptr = swin + (size_t)bidx * (Cc * HWc) + hw;
    const float* gptr = gru  + (size_t)bidx * (Cc * HWc) + hw;

    float sl[Cc], gl[Cc];
#pragma unroll
    for (int c = 0; c < Cc; ++c) { sl[c] = sptr[c * HWc]; gl[c] = gptr[c * HWc]; }

    float ms = sl[0], mg = gl[0];
#pragma unroll
    for (int c = 1; c < Cc; ++c) { ms = fmaxf(ms, sl[c]); mg = fmaxf(mg, gl[c]); }
    float es[Cc], eg[Cc];
    float ss = 0.f, sg = 0.f;
#pragma unroll
    for (int c = 0; c < Cc; ++c) {
        es[c] = __expf(sl[c] - ms);  ss += es[c];
        eg[c] = __expf(gl[c] - mg);  sg += eg[c];
    }
    const float invs = __builtin_amdgcn_rcpf(ss);
    const float invg = __builtin_amdgcn_rcpf(sg);

    float* fop = out + (size_t)bidx * (Cc * HWc) + hw;

#pragma unroll
    for (int c = 0; c < Cc; ++c) {
        const float sp = es[c] * invs;
        const float gp = eg[c] * invg;
        const float* w1c = W1 + c * (HIDc * 2);
        const float* b1c = b1 + c * HIDc;
        const float* w2c = W2 + c * (2 * HIDc);

        float a0 = b2[c * 2 + 0];
        float a1 = b2[c * 2 + 1];
#pragma unroll
        for (int k = 0; k < HIDc; ++k) {
            float h = fmaf(w1c[k * 2 + 0], sp, fmaf(w1c[k * 2 + 1], gp, b1c[k]));
            h = fmaxf(h, 0.f);
            a0 = fmaf(w2c[k], h, a0);
            a1 = fmaf(w2c[HIDc + k], h, a1);
        }
        const float d = a0 - a1;
        const float t = __expf(-fabsf(d));
        const float r = __builtin_amdgcn_rcpf(1.f + t);
        const float w0 = (d >= 0.f) ? r : 1.f - r;
        const float w1 = 1.f - w0;

        fop[c * HWc] = fmaf(w0, sl[c], w1 * gl[c]);
        dwbuf2[tid * Cc + ((c + tid) & (Cc - 1))] = make_float2(w0, w1);
    }

    __syncthreads();

    float2* outv2 = reinterpret_cast<float2*>(
        out + (size_t)FUSED_ELEMS + PREF_ELEMS + (size_t)blockIdx.x * (256 * Cc * 2));
#pragma unroll
    for (int j = 0; j < Cc; ++j) {
        const int pi = j * 256 + tid;
        const int p  = pi >> 4;
        const int pr = pi & (Cc - 1);
        outv2[pi] = dwbuf2[p * Cc + ((pr + p) & (Cc - 1))];
    }

    if (blockIdx.x == 0 && tid < PREF_ELEMS) {
        out[(size_t)FUSED_ELEMS + tid] = pref[tid];
    }
}

extern "C" void kernel_launch(void* const* d_in, const int* in_sizes, int n_in,
                              void* d_out, int out_size, void* d_ws, size_t ws_size,
                              hipStream_t stream) {
    const float* swin = (const float*)d_in[0];
    const float* gru  = (const float*)d_in[1];
    const float* W1   = (const float*)d_in[2];
    const float* b1   = (const float*)d_in[3];
    const float* W2   = (const float*)d_in[4];
    const float* b2   = (const float*)d_in[5];
    const float* pref = (const float*)d_in[6];
    float* out = (float*)d_out;

    if (ws_size >= (size_t)PACKED_BYTES) {
        v2f* ws = (v2f*)d_ws;
        hipLaunchKernelGGL(gate_prep, dim3(Cc), dim3(64), 0, stream, W1, b1, W2, b2, ws);
        hipLaunchKernelGGL(gate_main_packed2, dim3(Npix / PPB), dim3(TPB), 0, stream,
                           swin, gru, ws, pref, out);
    } else {
        hipLaunchKernelGGL(gate_main_scalar, dim3(Npix / 256), dim3(256), 0, stream,
                           swin, gru, W1, b1, W2, b2, pref, out);
    }
}